// Round 6
// baseline (81.788 us; speedup 1.0000x reference)
//
#include <hip/hip_runtime.h>

#define BSZ 512
#define NN 128
#define HEADS 8
#define DIN 64
#define DOUT 64

typedef __bf16 bf16x8 __attribute__((ext_vector_type(8)));
typedef float floatx4 __attribute__((ext_vector_type(4)));

static __device__ __forceinline__ unsigned short f2bf(float f) {
    __bf16 b = (__bf16)f;
    return __builtin_bit_cast(unsigned short, b);
}
static __device__ __forceinline__ bf16x8 ld_frag(const unsigned short* p) {
    uint4 r = *reinterpret_cast<const uint4*>(p);
    return __builtin_bit_cast(bf16x8, r);
}

// ---- prep: pack adj -> bitmasks; transpose w -> wT[h][o][k] bf16 ----
__global__ __launch_bounds__(512) void prep(
    const int* __restrict__ adj, const float* __restrict__ w,
    unsigned int* __restrict__ msk, unsigned short* __restrict__ wT, int do_w)
{
    const int b = blockIdx.x;
    const int t = threadIdx.x;          // 0..511: row = t>>2, word = t&3
    const int* ap = adj + (size_t)b * NN * NN + (t >> 2) * NN + (t & 3) * 32;
    unsigned int m = 0;
    #pragma unroll
    for (int q = 0; q < 8; ++q) {
        int4 v = *reinterpret_cast<const int4*>(ap + q * 4);
        m |= (v.x != 0 ? (1u << (4 * q + 0)) : 0u)
           | (v.y != 0 ? (1u << (4 * q + 1)) : 0u)
           | (v.z != 0 ? (1u << (4 * q + 2)) : 0u)
           | (v.w != 0 ? (1u << (4 * q + 3)) : 0u);
    }
    msk[b * 512 + t] = m;

    if (do_w && b < HEADS) {
        const float* wg = w + b * DIN * DOUT;
        const int o = t >> 3, k0 = (t & 7) * 8;
        unsigned int u[4];
        #pragma unroll
        for (int p = 0; p < 4; ++p) {
            float f0 = wg[(k0 + 2 * p) * DOUT + o];
            float f1 = wg[(k0 + 2 * p + 1) * DOUT + o];
            u[p] = f2bf(f0) | ((unsigned int)f2bf(f1) << 16);
        }
        *reinterpret_cast<uint4*>(&wT[b * DOUT * DIN + o * DIN + k0]) =
            make_uint4(u[0], u[1], u[2], u[3]);
    }
}

// ---- main: one block per (b, head); 512 threads; ONE barrier ----
__global__ __launch_bounds__(512, 6) void gat_fwd(
    const float* __restrict__ hin,          // [BSZ][NN][DIN]
    const unsigned int* __restrict__ mskg,  // [BSZ][NN][4]
    const unsigned short* __restrict__ wTg, // [HEADS][DOUT][DIN] bf16 (or null)
    const float* __restrict__ w,            // fallback
    const float* __restrict__ a_src,
    const float* __restrict__ a_dst,
    const float* __restrict__ bias,
    float* __restrict__ out)                // [BSZ][HEADS][NN][DOUT]
{
    __shared__ __attribute__((aligned(16))) unsigned short hpT[DOUT * NN];    // 16 KB [o][j]
    __shared__ __attribute__((aligned(16))) unsigned short P[NN * NN];        // 32 KB [i][j]
    __shared__ __attribute__((aligned(16))) float s_src[NN];
    __shared__ __attribute__((aligned(16))) float s_dst[NN];

    const int bid  = blockIdx.x;
    const int b    = bid >> 3;    // hd fast-varying: 8 head-blocks of b share h[b]/msk[b]
    const int hd   = bid & 7;
    const int tid  = threadIdx.x;
    const int lane = tid & 63;
    const int wv   = tid >> 6;
    const int lg   = lane >> 4;   // 0..3
    const int lm   = lane & 15;   // 0..15
    const int n0   = wv * 16;

    // h A-fragments straight to registers
    const float* hb = hin + (size_t)b * NN * DIN;
    bf16x8 hA[2];
    #pragma unroll
    for (int kt = 0; kt < 2; ++kt) {
        const float* p = hb + (n0 + lm) * DIN + kt * 32 + lg * 8;
        float4 v0 = *reinterpret_cast<const float4*>(p);
        float4 v1 = *reinterpret_cast<const float4*>(p + 4);
        bf16x8 a;
        a[0] = (__bf16)v0.x; a[1] = (__bf16)v0.y; a[2] = (__bf16)v0.z; a[3] = (__bf16)v0.w;
        a[4] = (__bf16)v1.x; a[5] = (__bf16)v1.y; a[6] = (__bf16)v1.z; a[7] = (__bf16)v1.w;
        hA[kt] = a;
    }
    const unsigned int mw = mskg[b * 512 + (n0 + lm) * 4 + lg];

    // ======== phase 1: GEMM1 ========
    floatx4 acc[4] = {floatx4{0,0,0,0}, floatx4{0,0,0,0}, floatx4{0,0,0,0}, floatx4{0,0,0,0}};
    if (wTg) {
        const unsigned short* wt = wTg + hd * DOUT * DIN;
        #pragma unroll
        for (int kt = 0; kt < 2; ++kt) {
            #pragma unroll
            for (int nt = 0; nt < 4; ++nt) {
                bf16x8 bfr = ld_frag(&wt[(nt * 16 + lm) * DIN + kt * 32 + lg * 8]);
                acc[nt] = __builtin_amdgcn_mfma_f32_16x16x32_bf16(hA[kt], bfr, acc[nt], 0, 0, 0);
            }
        }
    } else {
        const float* wg = w + hd * DIN * DOUT;
        #pragma unroll
        for (int kt = 0; kt < 2; ++kt) {
            #pragma unroll
            for (int nt = 0; nt < 4; ++nt) {
                const float* wp = wg + (kt * 32 + lg * 8) * DOUT + nt * 16 + lm;
                bf16x8 bfr;
                #pragma unroll
                for (int q = 0; q < 8; ++q) bfr[q] = (__bf16)wp[q * DOUT];
                acc[nt] = __builtin_amdgcn_mfma_f32_16x16x32_bf16(hA[kt], bfr, acc[nt], 0, 0, 0);
            }
        }
    }
    // tanh -> src/dst partial dots; hp -> hpT (bf16, transposed, swizzled)
    const float* asp = a_src + hd * DOUT;
    const float* adp = a_dst + hd * DOUT;
    float ps[4] = {0, 0, 0, 0}, pd[4] = {0, 0, 0, 0};
    #pragma unroll
    for (int nt = 0; nt < 4; ++nt) {
        const int o = nt * 16 + lm;
        const float as = asp[o], ad = adp[o];
        #pragma unroll
        for (int r = 0; r < 4; ++r) {
            const float v = acc[nt][r];
            const float ex = __expf(2.f * v);
            const float t = 1.f - 2.f / (ex + 1.f);   // tanh, exact formula
            ps[r] = fmaf(t, as, ps[r]);
            pd[r] = fmaf(t, ad, pd[r]);
        }
        const int jb = n0 + lg * 4;
        unsigned int u01 = f2bf(acc[nt][0]) | ((unsigned int)f2bf(acc[nt][1]) << 16);
        unsigned int u23 = f2bf(acc[nt][2]) | ((unsigned int)f2bf(acc[nt][3]) << 16);
        const int base = (o * 128 + jb) ^ ((o & 7) << 3);
        *reinterpret_cast<unsigned int*>(&hpT[base])     = u01;
        *reinterpret_cast<unsigned int*>(&hpT[base + 2]) = u23;
    }
    #pragma unroll
    for (int r = 0; r < 4; ++r) {
        #pragma unroll
        for (int m = 1; m <= 8; m <<= 1) {
            ps[r] += __shfl_xor(ps[r], m);
            pd[r] += __shfl_xor(pd[r], m);
        }
    }
    if (lm == 0) {
        #pragma unroll
        for (int r = 0; r < 4; ++r) {
            s_src[n0 + lg * 4 + r] = ps[r];
            s_dst[n0 + lg * 4 + r] = pd[r];
        }
    }
    __syncthreads();   // the only barrier

    // ======== phase 2: sparse max-free softmax + transposed GEMM2 ========
    const int i = n0 + lm;                 // this lane's row (4 lanes/row, lg = j-word)
    const int sw = (i & 7) << 3;
    const float si = s_src[i];

    const int pz = i * 128 + lg * 32;
    #pragma unroll
    for (int t = 0; t < 4; ++t)
        *reinterpret_cast<uint4*>(&P[(pz + 8 * t) ^ sw]) = make_uint4(0, 0, 0, 0);

    unsigned int m = mw;
    float sum = 0.f;
    while (m) {
        const int q = __builtin_ctz(m); m &= m - 1;
        const float x = si + s_dst[lg * 32 + q];
        const float xl = fmaxf(x, 0.f) + 0.2f * fminf(x, 0.f);  // leaky
        const float e = __expf(xl);                              // max-free: x bounded
        const __bf16 eb = (__bf16)e;
        sum += (float)eb;
        P[(pz + q) ^ sw] = __builtin_bit_cast(unsigned short, eb);
    }
    sum += __shfl_xor(sum, 16);
    sum += __shfl_xor(sum, 32);
    const float inv = 1.f / sum;   // row i=n0+lm's normalizer (all 4 lg-lanes agree)

    // D[row=o][col=i]: swap MFMA operands (A=hpT frag, B=P frag — same LDS reads)
    floatx4 oacc[4] = {floatx4{0,0,0,0}, floatx4{0,0,0,0}, floatx4{0,0,0,0}, floatx4{0,0,0,0}};
    #pragma unroll
    for (int kt = 0; kt < 4; ++kt) {
        const bf16x8 af = ld_frag(&P[(i * 128 + kt * 32 + lg * 8) ^ sw]);
        #pragma unroll
        for (int nt = 0; nt < 4; ++nt) {
            const int o = nt * 16 + lm;
            bf16x8 bfr = ld_frag(&hpT[(o * 128 + kt * 32 + lg * 8) ^ ((o & 7) << 3)]);
            oacc[nt] = __builtin_amdgcn_mfma_f32_16x16x32_bf16(bfr, af, oacc[nt], 0, 0, 0);
        }
    }
    // lane holds out[i=n0+lm][o = nt*16 + lg*4 + r], r=0..3 -> float4 stores
    float* outr = out + (((size_t)b * HEADS + hd) * NN + (n0 + lm)) * DOUT;
    #pragma unroll
    for (int nt = 0; nt < 4; ++nt) {
        const float4 bv = *reinterpret_cast<const float4*>(&bias[nt * 16 + lg * 4]);
        float4 st;
        st.x = fmaf(oacc[nt][0], inv, bv.x);
        st.y = fmaf(oacc[nt][1], inv, bv.y);
        st.z = fmaf(oacc[nt][2], inv, bv.z);
        st.w = fmaf(oacc[nt][3], inv, bv.w);
        *reinterpret_cast<float4*>(&outr[nt * 16 + lg * 4]) = st;
    }
}

extern "C" void kernel_launch(void* const* d_in, const int* in_sizes, int n_in,
                              void* d_out, int out_size, void* d_ws, size_t ws_size,
                              hipStream_t stream) {
    (void)in_sizes; (void)n_in; (void)out_size;
    const float* h     = (const float*)d_in[0];
    const int*   adj   = (const int*)d_in[1];
    const float* w     = (const float*)d_in[2];
    const float* a_src = (const float*)d_in[3];
    const float* a_dst = (const float*)d_in[4];
    const float* bias  = (const float*)d_in[5];
    float* out = (float*)d_out;

    unsigned int* msk = (unsigned int*)d_ws;                     // 1 MB
    const size_t MSK_BYTES = (size_t)BSZ * 512 * 4;
    unsigned short* wT = nullptr;
    const bool use_wt = ws_size >= MSK_BYTES + (size_t)HEADS * DOUT * DIN * 2;
    if (use_wt) wT = (unsigned short*)((char*)d_ws + MSK_BYTES); // 64 KB

    prep<<<dim3(BSZ), dim3(512), 0, stream>>>(adj, w, msk, wT, use_wt ? 1 : 0);
    gat_fwd<<<dim3(BSZ * HEADS), dim3(512), 0, stream>>>(h, msk, wT, w, a_src, a_dst, bias, out);
}

// Round 8
// 78.803 us; speedup vs baseline: 1.0379x; 1.0379x over previous
//
#include <hip/hip_runtime.h>

#define BSZ 512
#define NN 128
#define HEADS 8
#define DIN 64
#define DOUT 64

typedef __bf16 bf16x8 __attribute__((ext_vector_type(8)));
typedef float floatx4 __attribute__((ext_vector_type(4)));

static __device__ __forceinline__ unsigned short f2bf(float f) {
    __bf16 b = (__bf16)f;
    return __builtin_bit_cast(unsigned short, b);
}
static __device__ __forceinline__ bf16x8 ld_frag(const unsigned short* p) {
    uint4 r = *reinterpret_cast<const uint4*>(p);
    return __builtin_bit_cast(bf16x8, r);
}

// ---- prep: pack adj -> bitmasks; transpose w -> wT[h][o][k] bf16 ----
__global__ __launch_bounds__(512) void prep(
    const int* __restrict__ adj, const float* __restrict__ w,
    unsigned int* __restrict__ msk, unsigned short* __restrict__ wT, int do_w)
{
    const int b = blockIdx.x;
    const int t = threadIdx.x;          // 0..511: row = t>>2, word = t&3
    const int* ap = adj + (size_t)b * NN * NN + (t >> 2) * NN + (t & 3) * 32;
    unsigned int m = 0;
    #pragma unroll
    for (int q = 0; q < 8; ++q) {
        int4 v = *reinterpret_cast<const int4*>(ap + q * 4);
        m |= (v.x != 0 ? (1u << (4 * q + 0)) : 0u)
           | (v.y != 0 ? (1u << (4 * q + 1)) : 0u)
           | (v.z != 0 ? (1u << (4 * q + 2)) : 0u)
           | (v.w != 0 ? (1u << (4 * q + 3)) : 0u);
    }
    msk[b * 512 + t] = m;

    if (do_w && b < HEADS) {
        const float* wg = w + b * DIN * DOUT;
        const int o = t >> 3, k0 = (t & 7) * 8;
        unsigned int u[4];
        #pragma unroll
        for (int p = 0; p < 4; ++p) {
            float f0 = wg[(k0 + 2 * p) * DOUT + o];
            float f1 = wg[(k0 + 2 * p + 1) * DOUT + o];
            u[p] = f2bf(f0) | ((unsigned int)f2bf(f1) << 16);
        }
        *reinterpret_cast<uint4*>(&wT[b * DOUT * DIN + o * DIN + k0]) =
            make_uint4(u[0], u[1], u[2], u[3]);
    }
}

// ---- main: one block per (b, head); 512 threads; ONE barrier; 17.4 KB LDS ----
__global__ __launch_bounds__(512, 8) void gat_fwd(
    const float* __restrict__ hin,          // [BSZ][NN][DIN]
    const unsigned int* __restrict__ mskg,  // [BSZ][NN][4]
    const unsigned short* __restrict__ wTg, // [HEADS][DOUT][DIN] bf16 (or null)
    const float* __restrict__ w,            // fallback
    const float* __restrict__ a_src,
    const float* __restrict__ a_dst,
    const float* __restrict__ bias,
    float* __restrict__ out)                // [BSZ][HEADS][NN][DOUT]
{
    __shared__ __attribute__((aligned(16))) unsigned short hpT[DOUT * NN];  // 16 KB [o][j] swz
    __shared__ __attribute__((aligned(16))) float s_src[NN];
    __shared__ __attribute__((aligned(16))) float s_dst[NN];

    const int bid  = blockIdx.x;
    const int b    = bid >> 3;    // hd fast-varying: 8 head-blocks of b share h[b]/msk[b]
    const int hd   = bid & 7;
    const int tid  = threadIdx.x;
    const int lane = tid & 63;
    const int wv   = tid >> 6;
    const int lg   = lane >> 4;   // 0..3
    const int lm   = lane & 15;   // 0..15
    const int n0   = wv * 16;

    // h A-fragments straight to registers; mask row (uint4) prefetched early
    const float* hb = hin + (size_t)b * NN * DIN;
    bf16x8 hA[2];
    #pragma unroll
    for (int kt = 0; kt < 2; ++kt) {
        const float* p = hb + (n0 + lm) * DIN + kt * 32 + lg * 8;
        float4 v0 = *reinterpret_cast<const float4*>(p);
        float4 v1 = *reinterpret_cast<const float4*>(p + 4);
        bf16x8 a;
        a[0] = (__bf16)v0.x; a[1] = (__bf16)v0.y; a[2] = (__bf16)v0.z; a[3] = (__bf16)v0.w;
        a[4] = (__bf16)v1.x; a[5] = (__bf16)v1.y; a[6] = (__bf16)v1.z; a[7] = (__bf16)v1.w;
        hA[kt] = a;
    }
    const uint4 mr = *reinterpret_cast<const uint4*>(&mskg[(size_t)b * 512 + (n0 + lm) * 4]);
    unsigned int mwv[4] = {mr.x, mr.y, mr.z, mr.w};

    // ======== phase 1: GEMM1 ========
    floatx4 acc[4] = {floatx4{0,0,0,0}, floatx4{0,0,0,0}, floatx4{0,0,0,0}, floatx4{0,0,0,0}};
    if (wTg) {
        const unsigned short* wt = wTg + hd * DOUT * DIN;
        #pragma unroll
        for (int kt = 0; kt < 2; ++kt) {
            #pragma unroll
            for (int nt = 0; nt < 4; ++nt) {
                bf16x8 bfr = ld_frag(&wt[(nt * 16 + lm) * DIN + kt * 32 + lg * 8]);
                acc[nt] = __builtin_amdgcn_mfma_f32_16x16x32_bf16(hA[kt], bfr, acc[nt], 0, 0, 0);
            }
        }
    } else {
        const float* wg = w + hd * DIN * DOUT;
        #pragma unroll
        for (int kt = 0; kt < 2; ++kt) {
            #pragma unroll
            for (int nt = 0; nt < 4; ++nt) {
                const float* wp = wg + (kt * 32 + lg * 8) * DOUT + nt * 16 + lm;
                bf16x8 bfr;
                #pragma unroll
                for (int q = 0; q < 8; ++q) bfr[q] = (__bf16)wp[q * DOUT];
                acc[nt] = __builtin_amdgcn_mfma_f32_16x16x32_bf16(hA[kt], bfr, acc[nt], 0, 0, 0);
            }
        }
    }
    // tanh -> src/dst partial dots; hp -> hpT (bf16, transposed, swizzled)
    const float* asp = a_src + hd * DOUT;
    const float* adp = a_dst + hd * DOUT;
    float ps[4] = {0, 0, 0, 0}, pd[4] = {0, 0, 0, 0};
    #pragma unroll
    for (int nt = 0; nt < 4; ++nt) {
        const int o = nt * 16 + lm;
        const float as = asp[o], ad = adp[o];
        #pragma unroll
        for (int r = 0; r < 4; ++r) {
            const float v = acc[nt][r];
            const float ex = __expf(2.f * v);
            const float t = 1.f - 2.f / (ex + 1.f);   // tanh, exact formula
            ps[r] = fmaf(t, as, ps[r]);
            pd[r] = fmaf(t, ad, pd[r]);
        }
        const int jb = n0 + lg * 4;
        unsigned int u01 = f2bf(acc[nt][0]) | ((unsigned int)f2bf(acc[nt][1]) << 16);
        unsigned int u23 = f2bf(acc[nt][2]) | ((unsigned int)f2bf(acc[nt][3]) << 16);
        const int base = (o * 128 + jb) ^ ((o & 7) << 3);
        *reinterpret_cast<unsigned int*>(&hpT[base])     = u01;
        *reinterpret_cast<unsigned int*>(&hpT[base + 2]) = u23;
    }
    #pragma unroll
    for (int r = 0; r < 4; ++r) {
        #pragma unroll
        for (int m = 1; m <= 8; m <<= 1) {
            ps[r] += __shfl_xor(ps[r], m);
            pd[r] += __shfl_xor(pd[r], m);
        }
    }
    if (lm == 0) {
        #pragma unroll
        for (int r = 0; r < 4; ++r) {
            s_src[n0 + lg * 4 + r] = ps[r];
            s_dst[n0 + lg * 4 + r] = pd[r];
        }
    }
    __syncthreads();   // the only barrier

    // ======== phase 2: sparse softmax -> REGISTER P-fragments + GEMM2 ========
    const int i = n0 + lm;             // this lane's row; needs byte lg of each mask word
    const float si = s_src[i];

    float sum = 0.f;
    bf16x8 pf[4];
    #pragma unroll
    for (int kt = 0; kt < 4; ++kt) {
        unsigned long long d01 = 0ull, d23 = 0ull;   // slots 0..3 / 4..7 (static per kt)
        unsigned int byte = (mwv[kt] >> (lg * 8)) & 0xffu;
        while (byte) {
            const int q = __builtin_ctz(byte); byte &= byte - 1;
            const float x = si + s_dst[kt * 32 + lg * 8 + q];
            const float xl = fmaxf(x, 0.f) + 0.2f * fminf(x, 0.f);  // leaky
            const float e = __expf(xl);                              // max-free: x bounded
            const __bf16 eb = (__bf16)e;
            sum += (float)eb;                                        // sum of quantized e
            const unsigned long long v =
                (unsigned long long)__builtin_bit_cast(unsigned short, eb) << ((q & 3) * 16);
            if (q < 4) d01 |= v; else d23 |= v;                      // 2-way select, no scratch
        }
        const uint4 ui = make_uint4((unsigned)d01, (unsigned)(d01 >> 32),
                                    (unsigned)d23, (unsigned)(d23 >> 32));
        pf[kt] = __builtin_bit_cast(bf16x8, ui);
    }
    sum += __shfl_xor(sum, 16);
    sum += __shfl_xor(sum, 32);
    const float inv = 1.f / sum;   // row i's normalizer (all 4 lg-lanes agree)

    // transposed GEMM2: D[row=o][col=i], A = hpT frag, B = pf
    floatx4 oacc[4] = {floatx4{0,0,0,0}, floatx4{0,0,0,0}, floatx4{0,0,0,0}, floatx4{0,0,0,0}};
    #pragma unroll
    for (int kt = 0; kt < 4; ++kt) {
        #pragma unroll
        for (int nt = 0; nt < 4; ++nt) {
            const int o = nt * 16 + lm;
            bf16x8 bfr = ld_frag(&hpT[(o * 128 + kt * 32 + lg * 8) ^ ((o & 7) << 3)]);
            oacc[nt] = __builtin_amdgcn_mfma_f32_16x16x32_bf16(bfr, pf[kt], oacc[nt], 0, 0, 0);
        }
    }
    // lane holds out[i][o = nt*16 + lg*4 + r] -> nontemporal dwordx4 stores
    float* outr = out + (((size_t)b * HEADS + hd) * NN + i) * DOUT;
    #pragma unroll
    for (int nt = 0; nt < 4; ++nt) {
        const float4 bv = *reinterpret_cast<const float4*>(&bias[nt * 16 + lg * 4]);
        floatx4 st;
        st[0] = fmaf(oacc[nt][0], inv, bv.x);
        st[1] = fmaf(oacc[nt][1], inv, bv.y);
        st[2] = fmaf(oacc[nt][2], inv, bv.z);
        st[3] = fmaf(oacc[nt][3], inv, bv.w);
        __builtin_nontemporal_store(st, reinterpret_cast<floatx4*>(&outr[nt * 16 + lg * 4]));
    }
}

extern "C" void kernel_launch(void* const* d_in, const int* in_sizes, int n_in,
                              void* d_out, int out_size, void* d_ws, size_t ws_size,
                              hipStream_t stream) {
    (void)in_sizes; (void)n_in; (void)out_size;
    const float* h     = (const float*)d_in[0];
    const int*   adj   = (const int*)d_in[1];
    const float* w     = (const float*)d_in[2];
    const float* a_src = (const float*)d_in[3];
    const float* a_dst = (const float*)d_in[4];
    const float* bias  = (const float*)d_in[5];
    float* out = (float*)d_out;

    unsigned int* msk = (unsigned int*)d_ws;                     // 1 MB
    const size_t MSK_BYTES = (size_t)BSZ * 512 * 4;
    unsigned short* wT = nullptr;
    const bool use_wt = ws_size >= MSK_BYTES + (size_t)HEADS * DOUT * DIN * 2;
    if (use_wt) wT = (unsigned short*)((char*)d_ws + MSK_BYTES); // 64 KB

    prep<<<dim3(BSZ), dim3(512), 0, stream>>>(adj, w, msk, wT, use_wt ? 1 : 0);
    gat_fwd<<<dim3(BSZ * HEADS), dim3(512), 0, stream>>>(h, msk, wT, w, a_src, a_dst, bias, out);
}

// Round 9
// 75.411 us; speedup vs baseline: 1.0846x; 1.0450x over previous
//
#include <hip/hip_runtime.h>

#define BSZ 512
#define NN 128
#define HEADS 8
#define DIN 64
#define DOUT 64

typedef __bf16 bf16x8 __attribute__((ext_vector_type(8)));
typedef float floatx4 __attribute__((ext_vector_type(4)));

#define L2E 1.44269504f

static __device__ __forceinline__ unsigned short f2bf(float f) {
    __bf16 b = (__bf16)f;
    return __builtin_bit_cast(unsigned short, b);
}
static __device__ __forceinline__ bf16x8 ld_frag(const unsigned short* p) {
    uint4 r = *reinterpret_cast<const uint4*>(p);
    return __builtin_bit_cast(bf16x8, r);
}

// ---- prep: adj -> bitmasks; w -> wT[h][o][k] bf16; h -> bf16 ----
__global__ __launch_bounds__(512) void prep(
    const int* __restrict__ adj, const float* __restrict__ w,
    const float* __restrict__ h,
    unsigned int* __restrict__ msk, unsigned short* __restrict__ wT,
    unsigned short* __restrict__ hbf, int do_w, int do_h)
{
    const int b = blockIdx.x;
    const int t = threadIdx.x;          // 0..511: row = t>>2, word = t&3
    const int* ap = adj + (size_t)b * NN * NN + (t >> 2) * NN + (t & 3) * 32;
    unsigned int m = 0;
    #pragma unroll
    for (int q = 0; q < 8; ++q) {
        int4 v = *reinterpret_cast<const int4*>(ap + q * 4);
        m |= (v.x != 0 ? (1u << (4 * q + 0)) : 0u)
           | (v.y != 0 ? (1u << (4 * q + 1)) : 0u)
           | (v.z != 0 ? (1u << (4 * q + 2)) : 0u)
           | (v.w != 0 ? (1u << (4 * q + 3)) : 0u);
    }
    msk[b * 512 + t] = m;

    if (do_h) {   // h[b] -> bf16, 16 elems/thread
        const float* hp = h + (size_t)b * NN * DIN + t * 16;
        unsigned int u[8];
        #pragma unroll
        for (int p = 0; p < 4; ++p) {
            float4 v = *reinterpret_cast<const float4*>(hp + 4 * p);
            u[2 * p]     = f2bf(v.x) | ((unsigned int)f2bf(v.y) << 16);
            u[2 * p + 1] = f2bf(v.z) | ((unsigned int)f2bf(v.w) << 16);
        }
        unsigned short* dst = hbf + (size_t)b * NN * DIN + t * 16;
        *reinterpret_cast<uint4*>(dst)     = make_uint4(u[0], u[1], u[2], u[3]);
        *reinterpret_cast<uint4*>(dst + 8) = make_uint4(u[4], u[5], u[6], u[7]);
    }
    if (do_w && b < HEADS) {
        const float* wg = w + b * DIN * DOUT;
        const int o = t >> 3, k0 = (t & 7) * 8;
        unsigned int u[4];
        #pragma unroll
        for (int p = 0; p < 4; ++p) {
            float f0 = wg[(k0 + 2 * p) * DOUT + o];
            float f1 = wg[(k0 + 2 * p + 1) * DOUT + o];
            u[p] = f2bf(f0) | ((unsigned int)f2bf(f1) << 16);
        }
        *reinterpret_cast<uint4*>(&wT[b * DOUT * DIN + o * DIN + k0]) =
            make_uint4(u[0], u[1], u[2], u[3]);
    }
}

// ---- main: one block per (b, head); 512 threads; ONE barrier; 17.4 KB LDS ----
__global__ __launch_bounds__(512, 8) void gat_fwd(
    const float* __restrict__ hin,          // [BSZ][NN][DIN] (fallback)
    const unsigned short* __restrict__ hbfg,// [BSZ][NN][DIN] bf16 (or null)
    const unsigned int* __restrict__ mskg,  // [BSZ][NN][4]
    const unsigned short* __restrict__ wTg, // [HEADS][DOUT][DIN] bf16 (or null)
    const float* __restrict__ w,            // fallback
    const float* __restrict__ a_src,
    const float* __restrict__ a_dst,
    const float* __restrict__ bias,
    float* __restrict__ out)                // [BSZ][HEADS][NN][DOUT]
{
    __shared__ __attribute__((aligned(16))) unsigned short hpT[DOUT * NN];  // 16 KB [o][j] swz
    __shared__ __attribute__((aligned(16))) float s_src[NN];   // pre-scaled by log2(e)
    __shared__ __attribute__((aligned(16))) float s_dst[NN];   // pre-scaled by log2(e)

    const int bid  = blockIdx.x;
    const int b    = bid >> 3;    // hd fast-varying: 8 head-blocks of b share h[b]/msk[b]
    const int hd   = bid & 7;
    const int tid  = threadIdx.x;
    const int lane = tid & 63;
    const int wv   = tid >> 6;
    const int lg   = lane >> 4;   // 0..3
    const int lm   = lane & 15;   // 0..15
    const int n0   = wv * 16;

    // h A-fragments; mask row prefetched early
    bf16x8 hA[2];
    if (hbfg) {
        const unsigned short* hq = hbfg + ((size_t)b * NN + n0 + lm) * DIN + lg * 8;
        hA[0] = ld_frag(hq);
        hA[1] = ld_frag(hq + 32);
    } else {
        const float* hb = hin + (size_t)b * NN * DIN;
        #pragma unroll
        for (int kt = 0; kt < 2; ++kt) {
            const float* p = hb + (n0 + lm) * DIN + kt * 32 + lg * 8;
            float4 v0 = *reinterpret_cast<const float4*>(p);
            float4 v1 = *reinterpret_cast<const float4*>(p + 4);
            bf16x8 a;
            a[0] = (__bf16)v0.x; a[1] = (__bf16)v0.y; a[2] = (__bf16)v0.z; a[3] = (__bf16)v0.w;
            a[4] = (__bf16)v1.x; a[5] = (__bf16)v1.y; a[6] = (__bf16)v1.z; a[7] = (__bf16)v1.w;
            hA[kt] = a;
        }
    }
    const uint4 mr = *reinterpret_cast<const uint4*>(&mskg[(size_t)b * 512 + (n0 + lm) * 4]);
    unsigned int mwv[4] = {mr.x, mr.y, mr.z, mr.w};

    // ======== phase 1: GEMM1 ========
    floatx4 acc[4] = {floatx4{0,0,0,0}, floatx4{0,0,0,0}, floatx4{0,0,0,0}, floatx4{0,0,0,0}};
    if (wTg) {
        const unsigned short* wt = wTg + hd * DOUT * DIN;
        #pragma unroll
        for (int kt = 0; kt < 2; ++kt) {
            #pragma unroll
            for (int nt = 0; nt < 4; ++nt) {
                bf16x8 bfr = ld_frag(&wt[(nt * 16 + lm) * DIN + kt * 32 + lg * 8]);
                acc[nt] = __builtin_amdgcn_mfma_f32_16x16x32_bf16(hA[kt], bfr, acc[nt], 0, 0, 0);
            }
        }
    } else {
        const float* wg = w + hd * DIN * DOUT;
        #pragma unroll
        for (int kt = 0; kt < 2; ++kt) {
            #pragma unroll
            for (int nt = 0; nt < 4; ++nt) {
                const float* wp = wg + (kt * 32 + lg * 8) * DOUT + nt * 16 + lm;
                bf16x8 bfr;
                #pragma unroll
                for (int q = 0; q < 8; ++q) bfr[q] = (__bf16)wp[q * DOUT];
                acc[nt] = __builtin_amdgcn_mfma_f32_16x16x32_bf16(hA[kt], bfr, acc[nt], 0, 0, 0);
            }
        }
    }
    // tanh (fast rcp form) -> src/dst partial dots; hp -> hpT (bf16, swizzled)
    const float* asp = a_src + hd * DOUT;
    const float* adp = a_dst + hd * DOUT;
    float ps[4] = {0, 0, 0, 0}, pd[4] = {0, 0, 0, 0};
    #pragma unroll
    for (int nt = 0; nt < 4; ++nt) {
        const int o = nt * 16 + lm;
        const float as = asp[o], ad = adp[o];
        #pragma unroll
        for (int r = 0; r < 4; ++r) {
            const float v = acc[nt][r];
            // tanh(v) = 1 - 2/(e^{2v}+1);  e^{2v} = exp2(2*log2e*v)
            const float e2 = __builtin_amdgcn_exp2f(v * (2.f * L2E));
            const float t  = 1.f - 2.f * __builtin_amdgcn_rcpf(e2 + 1.f);
            ps[r] = fmaf(t, as, ps[r]);
            pd[r] = fmaf(t, ad, pd[r]);
        }
        const int jb = n0 + lg * 4;
        unsigned int u01 = f2bf(acc[nt][0]) | ((unsigned int)f2bf(acc[nt][1]) << 16);
        unsigned int u23 = f2bf(acc[nt][2]) | ((unsigned int)f2bf(acc[nt][3]) << 16);
        const int base = (o * 128 + jb) ^ ((o & 7) << 3);
        *reinterpret_cast<unsigned int*>(&hpT[base])     = u01;
        *reinterpret_cast<unsigned int*>(&hpT[base + 2]) = u23;
    }
    #pragma unroll
    for (int r = 0; r < 4; ++r) {
        #pragma unroll
        for (int m = 1; m <= 8; m <<= 1) {
            ps[r] += __shfl_xor(ps[r], m);
            pd[r] += __shfl_xor(pd[r], m);
        }
    }
    if (lm == 0) {
        #pragma unroll
        for (int r = 0; r < 4; ++r) {
            s_src[n0 + lg * 4 + r] = ps[r] * L2E;   // pre-scaled: exp(x) == exp2(x')
            s_dst[n0 + lg * 4 + r] = pd[r] * L2E;
        }
    }
    __syncthreads();   // the only barrier

    // ======== phase 2: sparse softmax -> REGISTER P-fragments + GEMM2 ========
    const int i = n0 + lm;             // this lane's row; needs byte lg of each mask word
    const float si = s_src[i];

    float sum = 0.f;
    bf16x8 pf[4];
    #pragma unroll
    for (int kt = 0; kt < 4; ++kt) {
        unsigned long long d01 = 0ull, d23 = 0ull;   // slots 0..3 / 4..7 (static per kt)
        unsigned int byte = (mwv[kt] >> (lg * 8)) & 0xffu;
        while (byte) {
            const int q = __builtin_ctz(byte); byte &= byte - 1;
            const float x = si + s_dst[kt * 32 + lg * 8 + q];     // log2-scaled logit
            const float xl = fmaxf(x, 0.f) + 0.2f * fminf(x, 0.f); // leaky (pos. homogeneous)
            const float e = __builtin_amdgcn_exp2f(xl);            // max-free: x bounded
            const __bf16 eb = (__bf16)e;
            sum += (float)eb;                                      // sum of quantized e
            const unsigned long long v =
                (unsigned long long)__builtin_bit_cast(unsigned short, eb) << ((q & 3) * 16);
            if (q < 4) d01 |= v; else d23 |= v;                    // 2-way select, no scratch
        }
        const uint4 ui = make_uint4((unsigned)d01, (unsigned)(d01 >> 32),
                                    (unsigned)d23, (unsigned)(d23 >> 32));
        pf[kt] = __builtin_bit_cast(bf16x8, ui);
    }
    sum += __shfl_xor(sum, 16);
    sum += __shfl_xor(sum, 32);
    const float inv = __builtin_amdgcn_rcpf(sum);  // row normalizer (sum >= e^0 = 1)

    // transposed GEMM2: D[row=o][col=i], A = hpT frag, B = pf
    floatx4 oacc[4] = {floatx4{0,0,0,0}, floatx4{0,0,0,0}, floatx4{0,0,0,0}, floatx4{0,0,0,0}};
    #pragma unroll
    for (int kt = 0; kt < 4; ++kt) {
        #pragma unroll
        for (int nt = 0; nt < 4; ++nt) {
            const int o = nt * 16 + lm;
            bf16x8 bfr = ld_frag(&hpT[(o * 128 + kt * 32 + lg * 8) ^ ((o & 7) << 3)]);
            oacc[nt] = __builtin_amdgcn_mfma_f32_16x16x32_bf16(bfr, pf[kt], oacc[nt], 0, 0, 0);
        }
    }
    // lane holds out[i][o = nt*16 + lg*4 + r] -> dwordx4 stores
    float* outr = out + (((size_t)b * HEADS + hd) * NN + i) * DOUT;
    #pragma unroll
    for (int nt = 0; nt < 4; ++nt) {
        const float4 bv = *reinterpret_cast<const float4*>(&bias[nt * 16 + lg * 4]);
        floatx4 st;
        st[0] = fmaf(oacc[nt][0], inv, bv.x);
        st[1] = fmaf(oacc[nt][1], inv, bv.y);
        st[2] = fmaf(oacc[nt][2], inv, bv.z);
        st[3] = fmaf(oacc[nt][3], inv, bv.w);
        *reinterpret_cast<floatx4*>(&outr[nt * 16 + lg * 4]) = st;
    }
}

extern "C" void kernel_launch(void* const* d_in, const int* in_sizes, int n_in,
                              void* d_out, int out_size, void* d_ws, size_t ws_size,
                              hipStream_t stream) {
    (void)in_sizes; (void)n_in; (void)out_size;
    const float* h     = (const float*)d_in[0];
    const int*   adj   = (const int*)d_in[1];
    const float* w     = (const float*)d_in[2];
    const float* a_src = (const float*)d_in[3];
    const float* a_dst = (const float*)d_in[4];
    const float* bias  = (const float*)d_in[5];
    float* out = (float*)d_out;

    const size_t MSK_BYTES = (size_t)BSZ * 512 * 4;            // 1 MB
    const size_t WT_BYTES  = (size_t)HEADS * DOUT * DIN * 2;   // 64 KB
    const size_t HBF_BYTES = (size_t)BSZ * NN * DIN * 2;       // 8.4 MB

    unsigned int*   msk = (unsigned int*)d_ws;
    unsigned short* wT  = nullptr;
    unsigned short* hbf = nullptr;
    const bool use_wt = ws_size >= MSK_BYTES + WT_BYTES;
    const bool use_h  = ws_size >= MSK_BYTES + WT_BYTES + HBF_BYTES;
    if (use_wt) wT  = (unsigned short*)((char*)d_ws + MSK_BYTES);
    if (use_h)  hbf = (unsigned short*)((char*)d_ws + MSK_BYTES + WT_BYTES);

    prep<<<dim3(BSZ), dim3(512), 0, stream>>>(adj, w, h, msk, wT, hbf,
                                              use_wt ? 1 : 0, use_h ? 1 : 0);
    gat_fwd<<<dim3(BSZ * HEADS), dim3(512), 0, stream>>>(h, hbf, msk, wT, w,
                                                         a_src, a_dst, bias, out);
}